// Round 9
// baseline (184.862 us; speedup 1.0000x reference)
//
#include <hip/hip_runtime.h>
#include <stdint.h>
#include <stddef.h>

// Problem geometry (B=4, S=2048, DIN=4096, DOUT=4096)
constexpr int MDIM = 8192;   // B*S
constexpr int NDIM = 4096;   // DOUT
constexpr int KDIM = 4096;   // DIN

using f32x4 = __attribute__((ext_vector_type(4))) float;
using s16x4 = __attribute__((ext_vector_type(4))) short;
using s16x8 = __attribute__((ext_vector_type(8))) short;
using i32x4 = __attribute__((ext_vector_type(4))) int;

__device__ __forceinline__ short f32_to_bf16_rn(float f) {
  union { float f; uint32_t u; } v; v.f = f;
  uint32_t r = (v.u + 0x7FFFu + ((v.u >> 16) & 1u)) >> 16;  // RTN-even
  return (short)(uint16_t)r;
}

// ---------------- prepass 1: x f32 -> i8, per-row symmetric scale ----------------
__global__ void __launch_bounds__(256) quant_x_kernel(const float* __restrict__ in,
                                                      signed char* __restrict__ out,
                                                      float* __restrict__ sx) {
  const int row = blockIdx.x;
  const int t   = threadIdx.x;
  const float* rp = in + (size_t)row * KDIM;
  f32x4 v[4];
  float m = 0.0f;
#pragma unroll
  for (int j = 0; j < 4; ++j) {
    v[j] = *(const f32x4*)(rp + t * 16 + j * 4);
#pragma unroll
    for (int e = 0; e < 4; ++e) m = fmaxf(m, __builtin_fabsf(v[j][e]));
  }
#pragma unroll
  for (int off = 32; off > 0; off >>= 1) m = fmaxf(m, __shfl_xor(m, off, 64));
  __shared__ float wmax[4];
  const int wv = t >> 6, ln = t & 63;
  if (ln == 0) wmax[wv] = m;
  __syncthreads();
  m = fmaxf(fmaxf(wmax[0], wmax[1]), fmaxf(wmax[2], wmax[3]));
  const float inv = (m > 0.0f) ? (127.0f / m) : 0.0f;
  if (t == 0) sx[row] = m * (1.0f / 127.0f);
  i32x4 o;
#pragma unroll
  for (int j = 0; j < 4; ++j) {
    int b[4];
#pragma unroll
    for (int e = 0; e < 4; ++e) {
      int q = (int)rintf(v[j][e] * inv);
      q = q < -127 ? -127 : (q > 127 ? 127 : q);
      b[e] = q & 255;
    }
    o[j] = b[0] | (b[1] << 8) | (b[2] << 16) | (b[3] << 24);
  }
  *(i32x4*)(out + (size_t)row * KDIM + t * 16) = o;
}

// ---------------- prepass 2: weight int32 -> i8 (exact, low-byte pack) ----------------
__global__ void __launch_bounds__(256) quant_w_kernel(const int* __restrict__ in,
                                                      signed char* __restrict__ out, int n16) {
  int i = blockIdx.x * 256 + threadIdx.x;
  const int stride = gridDim.x * 256;
  for (; i < n16; i += stride) {
    const i32x4* p = (const i32x4*)(in + (size_t)i * 16);
    i32x4 o;
#pragma unroll
    for (int j = 0; j < 4; ++j) {
      i32x4 a = p[j];
      o[j] = (a[0] & 255) | ((a[1] & 255) << 8) | ((a[2] & 255) << 16) | ((a[3] & 255) << 24);
    }
    *(i32x4*)(out + (size_t)i * 16) = o;
  }
}

// =====================================================================
// 256x256 i8 GEMM, BK=128, round-3-proven 4-phase structure, 1 block/CU.
//   A [M][K] i8 (per-row scaled x), Bw [N][K] i8 (exact weight)
//   out = (i32 acc) * sx[row] * s_w + bias[col]
// LDS 128 KiB: A@0, B@65536; per matrix per buffer 32 KiB laid out as
// [khalf h:2][256 rows][64 B], each 16-KB region using the PROVEN round-3/8
// zero-conflict geometry: XOR swizzle phys = lin ^ (((lin>>9)&1)<<5) within
// each 8-KB chunk, frag-read laneoff = (l15*64 + lh*16) ^ ((l15&8)<<2).
//
// Per K-tile t (cur=t&1), 4 phases x {reads ; stage ; BAR ; 16 MFMA ; BAR}:
//  ph1: rd bf=B(cur,h0)[4] + af=A0-3(cur,h0)[4]; stage B(t+1) [4 GLL]
//  ph2: rd ag=A4-7(cur,h0)[4];                   stage A(t+1) [4 GLL]
//  ph3: rd bf=B(cur,h1)[4] + af=A0-3(cur,h1)[4]
//  ph4: rd ag=A4-7(cur,h1)[4]; MFMA; vmcnt(0)* ; BAR   (*only if staged)
// RAW: {B,A}(t+1) staged ph1/ph2(t), drained by vmcnt(0)@ph4(t) — issued
//   2-3 phases (~1500 cyc) earlier >> 900-cyc HBM latency -> non-stalling.
// WAR: stage@ph1(t) overwrites B(t-1) whose last reads (ph3(t-1)) completed
//   (lgkm before their MFMA) >= 2 barriers earlier; stage@ph2(t) overwrites
//   A(t-1) last read ph4(t-1), >= 3 barriers earlier. Safe.
// Tail: t=31 stages nothing, no trailing vmcnt needed.
// =====================================================================

#define BAR asm volatile("s_barrier" ::: "memory")
#define WAITVM(n) asm volatile("s_waitcnt vmcnt(" #n ")" ::: "memory")

#define GLL(src, dst) __builtin_amdgcn_global_load_lds(                     \
    (const __attribute__((address_space(1))) void*)(src),                   \
    (__attribute__((address_space(3))) void*)(dst), 16, 0, 0)

// grow: const char* global row base, row stride 4096 B (i8). 4 GLL/wave.
#define STG4(grow, ldsmat, tau) do {                                        \
  const int buf_ = (tau) & 1;                                               \
  _Pragma("unroll") for (int h_ = 0; h_ < 2; ++h_)                          \
  _Pragma("unroll") for (int rh_ = 0; rh_ < 2; ++rh_)                       \
    GLL((grow) + (size_t)(rh_ * 128 + r0) * 4096 + (size_t)(tau) * 128      \
            + h_ * 64 + cb,                                                 \
        lds + (ldsmat) + buf_ * 32768 + h_ * 16384 + rh_ * 8192 + t * 16);  \
} while (0)

#define LDA8(bufc, fi, h) (*(const i32x4*)(lds + (bufc) * 32768             \
    + (h) * 16384 + wmoff + (fi) * 1024 + laneoff))
#define LDB8(bufc, fj, h) (*(const i32x4*)(lds + 65536 + (bufc) * 32768     \
    + (h) * 16384 + wnoff + (fj) * 1024 + laneoff))

#define MFMAQ(base, afr) do {                                               \
  __builtin_amdgcn_s_setprio(1);                                            \
  _Pragma("unroll") for (int i_ = 0; i_ < 4; ++i_)                          \
  _Pragma("unroll") for (int j_ = 0; j_ < 4; ++j_)                          \
    acc[(base) + i_][j_] = __builtin_amdgcn_mfma_i32_16x16x64_i8(           \
        afr[i_], bf[j_], acc[(base) + i_][j_], 0, 0, 0);                    \
  __builtin_amdgcn_s_setprio(0);                                            \
} while (0)

#define KT128(t_, cur, stg) do {                                            \
  /* ph1: h0, A-rows 0-3 */                                                 \
  _Pragma("unroll") for (int j_ = 0; j_ < 4; ++j_) bf[j_] = LDB8(cur, j_, 0); \
  _Pragma("unroll") for (int i_ = 0; i_ < 4; ++i_) af[i_] = LDA8(cur, i_, 0); \
  if (stg) STG4(Brow, 65536, (t_) + 1);                                     \
  BAR; MFMAQ(0, af); BAR;                                                   \
  /* ph2: h0, A-rows 4-7 (bf reused) */                                     \
  _Pragma("unroll") for (int i_ = 0; i_ < 4; ++i_) ag[i_] = LDA8(cur, 4 + i_, 0); \
  if (stg) STG4(Arow, 0, (t_) + 1);                                         \
  BAR; MFMAQ(4, ag); BAR;                                                   \
  /* ph3: h1, A-rows 0-3 */                                                 \
  _Pragma("unroll") for (int j_ = 0; j_ < 4; ++j_) bf[j_] = LDB8(cur, j_, 1); \
  _Pragma("unroll") for (int i_ = 0; i_ < 4; ++i_) af[i_] = LDA8(cur, i_, 1); \
  BAR; MFMAQ(0, af); BAR;                                                   \
  /* ph4: h1, A-rows 4-7 */                                                 \
  _Pragma("unroll") for (int i_ = 0; i_ < 4; ++i_) ag[i_] = LDA8(cur, 4 + i_, 1); \
  BAR; MFMAQ(4, ag);                                                        \
  if (stg) WAITVM(0);                                                       \
  BAR;                                                                      \
} while (0)

__global__ void __launch_bounds__(512, 2) gemm_i8_pipe(
    const signed char* __restrict__ A, const signed char* __restrict__ Bw,
    const float* __restrict__ sx, const float* __restrict__ scale_p,
    const float* __restrict__ bias, float* __restrict__ out) {
  __shared__ __align__(16) char lds[131072];

  const int t      = threadIdx.x;        // 0..511
  const int lane   = t & 63;
  const int wave   = t >> 6;
  const int wm     = wave >> 2;          // 0..1  (row half: 128 rows)
  const int wn     = wave & 3;           // 0..3  (col quarter: 64 cols)
  const int lane15 = lane & 15;
  const int lh     = lane >> 4;          // 0..3

  // round-3/8-proven zero-conflict swizzled read offset (XOR, not '+').
  const int laneoff = (lane15 * 64 + lh * 16) ^ ((lane15 & 8) << 2);
  const int wmoff   = wm * 8192;         // 128 rows * 64 B
  const int wnoff   = wn * 4096;         //  64 rows * 64 B

  // round-8-proven stage decode per 8-KB chunk:
  // slot o = t*16 holds element a = o ^ (((o>>9)&1)<<5)
  const int ax = ((t >> 5) & 1) << 5;
  const int a0 = (t * 16) ^ ax;
  const int r0 = a0 >> 6;                // row 0..127 within chunk
  const int cb = a0 & 63;                // K-byte within 64B half-row

  // XCD-aware swizzle: nwg = 512 (divisible by 8)
  const int bid   = blockIdx.x;
  const int wg    = (bid & 7) * 64 + (bid >> 3);
  const int ntile = wg & 15;             // 16 n-tiles
  const int mtile = wg >> 4;             // 32 m-tiles
  const int m0 = mtile * 256;
  const int n0 = ntile * 256;

  const char* Arow = (const char*)(A + (size_t)m0 * KDIM);
  const char* Brow = (const char*)(Bw + (size_t)n0 * KDIM);

  i32x4 acc[8][4] = {};
  i32x4 af[4], ag[4], bf[4];

  // Prologue: tile 0 only; full drain once (HBM latency paid once).
  STG4(Brow, 65536, 0);
  STG4(Arow, 0,     0);
  WAITVM(0);
  BAR;

  // Main: 32 K-tiles (BK=128); pairs keep buf index compile-time.
#pragma unroll 1
  for (int tp = 0; tp < 15; ++tp) {
    KT128(2 * tp,     0, 1);
    KT128(2 * tp + 1, 1, 1);
  }
  KT128(30, 0, 1);   // stages tile 31
  KT128(31, 1, 0);   // no stage, no drain needed

  // Epilogue: D layout col=lane&15, row=(lane>>4)*4+q (shape-determined,
  // dtype-independent — m89/m121-128). out = acc * sx[row]*sw + bias.
  const float sw = scale_p[0];
  float bv[4];
#pragma unroll
  for (int j = 0; j < 4; ++j) bv[j] = bias[n0 + wn * 64 + j * 16 + lane15];
#pragma unroll
  for (int i = 0; i < 8; ++i) {
    const int rowb = m0 + wm * 128 + i * 16 + lh * 4;
    float sxq[4];
#pragma unroll
    for (int q = 0; q < 4; ++q) sxq[q] = sx[rowb + q] * sw;
#pragma unroll
    for (int j = 0; j < 4; ++j) {
      const int col = n0 + wn * 64 + j * 16 + lane15;
#pragma unroll
      for (int q = 0; q < 4; ++q)
        out[(size_t)(rowb + q) * NDIM + col] = (float)acc[i][j][q] * sxq[q] + bv[j];
    }
  }
}

// ---------------- fallback: m97-style bf16 reg-staging (ws too small) ----------------
constexpr int FTILE = 128;
constexpr int FBK   = 64;

__global__ void __launch_bounds__(256) gemm_raw(
    const float* __restrict__ X, const int* __restrict__ W,
    const float* __restrict__ scale_p, const float* __restrict__ bias,
    float* __restrict__ out) {
  __shared__ short As[FTILE * FBK];
  __shared__ short Bs[FTILE * FBK];

  const int t      = threadIdx.x;
  const int lane   = t & 63;
  const int wave   = t >> 6;
  const int wm     = wave >> 1;
  const int wn     = wave & 1;
  const int lane15   = lane & 15;
  const int laneHalf = lane >> 4;

  const int bid   = blockIdx.x;
  const int wg    = (bid & 7) * 256 + (bid >> 3);
  const int ntile = wg & 31;
  const int mtile = wg >> 5;
  const int m0 = mtile * FTILE;
  const int n0 = ntile * FTILE;

  f32x4 acc[4][4] = {};

  for (int k0 = 0; k0 < KDIM; k0 += FBK) {
    __syncthreads();
#pragma unroll
    for (int r = 0; r < 8; ++r) {
      const int f   = r * 256 + t;
      const int row = f >> 4;
      const int c4  = (f & 15) * 4;
      f32x4 v = *(const f32x4*)(X + (size_t)(m0 + row) * KDIM + (k0 + c4));
      s16x4 h;
#pragma unroll
      for (int j = 0; j < 4; ++j) h[j] = f32_to_bf16_rn(v[j]);
      *(s16x4*)&As[row * FBK + c4] = h;

      i32x4 wv = *(const i32x4*)(W + (size_t)(n0 + row) * KDIM + (k0 + c4));
      s16x4 hw;
#pragma unroll
      for (int j = 0; j < 4; ++j) hw[j] = f32_to_bf16_rn((float)wv[j]);
      *(s16x4*)&Bs[row * FBK + c4] = hw;
    }
    __syncthreads();

#pragma unroll
    for (int kk = 0; kk < FBK; kk += 32) {
      const int kb = kk + laneHalf * 8;
      s16x8 af[4], bf[4];
#pragma unroll
      for (int i = 0; i < 4; ++i) {
        af[i] = *(const s16x8*)&As[(wm * 64 + i * 16 + lane15) * FBK + kb];
        bf[i] = *(const s16x8*)&Bs[(wn * 64 + i * 16 + lane15) * FBK + kb];
      }
#pragma unroll
      for (int i = 0; i < 4; ++i)
#pragma unroll
        for (int j = 0; j < 4; ++j)
          acc[i][j] = __builtin_amdgcn_mfma_f32_16x16x32_bf16(af[i], bf[j], acc[i][j], 0, 0, 0);
    }
  }

  const float s = scale_p[0];
#pragma unroll
  for (int j = 0; j < 4; ++j) {
    const int col = n0 + wn * 64 + j * 16 + lane15;
    const float bv = bias[col];
#pragma unroll
    for (int i = 0; i < 4; ++i) {
      const int row = m0 + wm * 64 + i * 16 + laneHalf * 4;
#pragma unroll
      for (int q = 0; q < 4; ++q)
        out[(size_t)(row + q) * NDIM + col] = acc[i][j][q] * s + bv;
    }
  }
}

extern "C" void kernel_launch(void* const* d_in, const int* in_sizes, int n_in,
                              void* d_out, int out_size, void* d_ws, size_t ws_size,
                              hipStream_t stream) {
  const float* x     = (const float*)d_in[0];
  const int*   w     = (const int*)d_in[1];    // integer inputs materialize as int32
  const float* scale = (const float*)d_in[2];
  const float* bias  = (const float*)d_in[3];
  float* out = (float*)d_out;

  const size_t a_bytes = (size_t)MDIM * KDIM;            // 33,554,432 (i8)
  const size_t b_bytes = (size_t)NDIM * KDIM;            // 16,777,216 (i8)
  const size_t need    = a_bytes + b_bytes + MDIM * 4;   // + sx floats

  if (ws_size >= need) {
    signed char* Ai8 = (signed char*)d_ws;
    signed char* Bi8 = Ai8 + a_bytes;
    float*       sxp = (float*)(Bi8 + b_bytes);
    quant_x_kernel<<<MDIM, 256, 0, stream>>>(x, Ai8, sxp);
    quant_w_kernel<<<4096, 256, 0, stream>>>(w, Bi8, (int)(b_bytes / 16));
    const int nwg = (MDIM / 256) * (NDIM / 256);  // 32*16 = 512
    gemm_i8_pipe<<<nwg, 512, 0, stream>>>(Ai8, Bi8, sxp, scale, bias, out);
  } else {
    const int nwg = (MDIM / FTILE) * (NDIM / FTILE);  // 2048
    gemm_raw<<<nwg, 256, 0, stream>>>(x, w, scale, bias, out);
  }
}